// Round 4
// baseline (3285.884 us; speedup 1.0000x reference)
//
#include <hip/hip_runtime.h>
#include <math.h>

#define NN 4096
#define WW 12
#define HH 256
#define PP 10
#define EE 131072
#define HS 262144
#define HMASK (HS-1)
#define TS 1024          // table intervals (1025 sample points)
#define TA 12.0f         // table half-domain: a in [-TA, TA]
#define NBLK 256         // persistent-kernel grid: 1 block per CU (co-resident)

typedef __attribute__((ext_vector_type(8))) short short8v;   // 8 x bf16 (A/B frag)
typedef __attribute__((ext_vector_type(4))) float f32x4;     // C/D frag

__device__ __forceinline__ float fast_tanh(float x){
  float e = __expf(2.0f*x);
  return 1.0f - 2.0f/(e+1.0f);   // exact identity (e^2x-1)/(e^2x+1)
}
__device__ __forceinline__ float fast_sigmoid(float x){
  return 1.0f/(1.0f+__expf(-x));
}
__device__ __forceinline__ unsigned short f2bf(float f){     // RNE fp32->bf16
  union{float f; unsigned u;} v; v.f = f;
  unsigned r = v.u + 0x7FFF + ((v.u>>16)&1);
  return (unsigned short)(r>>16);
}
__device__ __forceinline__ float bf2f(unsigned short h){
  union{unsigned u; float f;} v; v.u = ((unsigned)h)<<16; return v.f;
}
__device__ __forceinline__ void cvt8(const float4 x0, const float4 x1,
                                     short8v* oh, short8v* ol){
  float f[8] = {x0.x,x0.y,x0.z,x0.w,x1.x,x1.y,x1.z,x1.w};
  short h8[8], l8[8];
  #pragma unroll
  for (int j = 0; j < 8; ++j){
    unsigned short hh_ = f2bf(f[j]);
    h8[j] = (short)hh_;
    l8[j] = (short)f2bf(f[j] - bf2f(hh_));
  }
  *oh = *(short8v*)h8; *ol = *(short8v*)l8;
}

// device-wide sense barrier (all NBLK blocks co-resident: grid == #CUs)
__device__ __forceinline__ void gbar(int* cnt, int* gen, int nb){
  __syncthreads();
  if (threadIdx.x == 0){
    __threadfence();
    int g = __hip_atomic_load(gen, __ATOMIC_SEQ_CST, __HIP_MEMORY_SCOPE_AGENT);
    int t = __hip_atomic_fetch_add(cnt, 1, __ATOMIC_SEQ_CST, __HIP_MEMORY_SCOPE_AGENT);
    if (t == nb-1){
      __hip_atomic_store(cnt, 0, __ATOMIC_RELAXED, __HIP_MEMORY_SCOPE_AGENT);
      __hip_atomic_fetch_add(gen, 1, __ATOMIC_SEQ_CST, __HIP_MEMORY_SCOPE_AGENT);
    } else {
      while (__hip_atomic_load(gen, __ATOMIC_SEQ_CST, __HIP_MEMORY_SCOPE_AGENT) == g)
        __builtin_amdgcn_s_sleep(2);
    }
    __threadfence();
  }
  __syncthreads();
}

// ---------------- setup kernels ----------------

__global__ void k_init(const float* __restrict__ x, int* keys, int* midx,
                       float* deg, int* cnt, float* ring, float* hA,
                       int* count, int* bar_cnt, int* bar_gen){
  int i = blockIdx.x*256 + threadIdx.x;
  if (i < HS){ keys[i] = -1; midx[i] = -1; }
  if (i < NN){ deg[i] = 0.0f; cnt[i] = 0; }
  if (i < NN*WW) ring[i] = x[i];
  if (i < NN*HH) hA[i] = 0.0f;
  if (i == 0){ *count = 0; *bar_cnt = 0; *bar_gen = 0; }
}

// dedupe: numpy fancy assignment => last (max-index) edge wins per (src,dst)
__global__ void k_insert(const int* __restrict__ ei, int* keys, int* midx){
  int e = blockIdx.x*256 + threadIdx.x;
  if (e >= EE) return;
  int key = ei[e]*NN + ei[EE+e];
  unsigned h = (((unsigned)key)*2654435761u >> 14) & HMASK;
  for(;;){
    int k = keys[h];
    if (k == key){ atomicMax(&midx[h], e); return; }
    if (k == -1){
      int old = atomicCAS(&keys[h], -1, key);
      if (old == -1 || old == key){ atomicMax(&midx[h], e); return; }
    }
    h = (h+1) & HMASK;
  }
}

__global__ void k_compact(const int* __restrict__ ei, const float* __restrict__ ew,
                          const int* __restrict__ keys, const int* __restrict__ midx,
                          int* wsrc, int* wdst, float* wwt,
                          float* deg, int* cnt, int* count){
  int e = blockIdx.x*256 + threadIdx.x;
  if (e >= EE) return;
  int src = ei[e], dst = ei[EE+e];
  int key = src*NN + dst;
  unsigned h = (((unsigned)key)*2654435761u >> 14) & HMASK;
  while (keys[h] != key) h = (h+1) & HMASK;
  if (midx[h] == e){            // this edge is the winner for (src,dst)
    int p = atomicAdd(count, 1);
    wsrc[p] = src; wdst[p] = dst; wwt[p] = ew[e];
    atomicAdd(&deg[src], ew[e]);   // deg = row-sum of deduped adj (self-loop +1 later)
    atomicAdd(&cnt[dst], 1);       // CSR histogram keyed by dst (L uses adj^T)
  }
}

__global__ __launch_bounds__(1024) void k_scan(const int* __restrict__ cnt,
                                               int* row_start, int* fill){
  __shared__ int sd[NN];
  int tid = threadIdx.x;
  for (int i = tid; i < NN; i += 1024) sd[i] = cnt[i];
  __syncthreads();
  for (int off = 1; off < NN; off <<= 1){
    int v[4];
    #pragma unroll
    for (int r = 0; r < 4; ++r){
      int i = tid + r*1024;
      v[r] = (i >= off) ? sd[i-off] : 0;
    }
    __syncthreads();
    #pragma unroll
    for (int r = 0; r < 4; ++r) sd[tid + r*1024] += v[r];
    __syncthreads();
  }
  for (int i = tid; i < NN; i += 1024){
    int incl = sd[i];
    row_start[i+1] = incl;
    fill[i] = incl - cnt[i];   // exclusive prefix = scatter cursor
  }
  if (tid == 0) row_start[0] = 0;
}

// scatter + inline coef = wwt * d[src] * d[dst], d = 1/sqrt(deg+1)
__global__ void k_scatter(const int* __restrict__ wsrc, const int* __restrict__ wdst,
                          const float* __restrict__ wwt, const float* __restrict__ deg,
                          int* fill, int* csr_src, float* csr_cf,
                          const int* __restrict__ count){
  int p = blockIdx.x*256 + threadIdx.x;
  if (p >= *count) return;
  int s = wsrc[p], d = wdst[p];
  float c = wwt[p] * (1.0f/sqrtf(deg[s]+1.0f)) * (1.0f/sqrtf(deg[d]+1.0f));
  int pos = atomicAdd(&fill[d], 1);
  csr_src[pos] = s;
  csr_cf[pos] = c;
}

// table build: tab[w][s][h] = sum_c tanh(a_s*gw[c]) * ta_w[w*256+c, h]
__global__ __launch_bounds__(256) void k_tab(const float* __restrict__ gcn_w,
                                             const float* __restrict__ ta_w,
                                             float* __restrict__ tab){
  __shared__ float As[32][64];
  __shared__ float Bs[32][64];
  __shared__ float gws[256];
  int tid = threadIdx.x;
  int n0 = blockIdx.x*64;        // h tile
  int m0 = blockIdx.y*64;        // sample tile
  int w  = blockIdx.z;
  gws[tid] = gcn_w[tid];
  __syncthreads();
  float acc[4][4] = {};
  int tm = tid >> 4, tn = tid & 15;
  const float astep = 2.0f*TA/TS;
  for (int k0 = 0; k0 < 256; k0 += 32){
    #pragma unroll
    for (int r = 0; r < 2; ++r){
      int f = tid + r*256;
      int kk = f >> 4, n4 = (f & 15)*4;
      *(float4*)&Bs[kk][n4] = *(const float4*)&ta_w[(w*256 + k0+kk)*HH + n0 + n4];
    }
    {
      int kk = tid >> 3;
      int mb = (tid & 7)*8;
      float gw = gws[k0 + kk];
      #pragma unroll
      for (int i2 = 0; i2 < 8; ++i2){
        float a = -TA + (float)(m0 + mb + i2)*astep;
        As[kk][mb+i2] = fast_tanh(a*gw);
      }
    }
    __syncthreads();
    #pragma unroll
    for (int kk = 0; kk < 32; ++kk){
      float4 a4 = *(float4*)&As[kk][tm*4];
      float4 b4 = *(float4*)&Bs[kk][tn*4];
      float a[4] = {a4.x,a4.y,a4.z,a4.w};
      float b[4] = {b4.x,b4.y,b4.z,b4.w};
      #pragma unroll
      for (int i = 0; i < 4; ++i)
        #pragma unroll
        for (int j = 0; j < 4; ++j)
          acc[i][j] = fmaf(a[i], b[j], acc[i][j]);
    }
    __syncthreads();
  }
  #pragma unroll
  for (int i = 0; i < 4; ++i){
    int row = m0 + tm*4 + i;
    if (row <= TS){
      #pragma unroll
      for (int j = 0; j < 4; ++j)
        tab[((size_t)w*(TS+1) + row)*HH + n0 + tn*4 + j] = acc[i][j];
    }
  }
}

// pack GRU weights into MFMA B-fragment order, bf16 hi/lo planes (run once).
// groups g: 0=r, 1=z, 2=xn (K 0..255), 3=hn (K 256..511).
// layout: [ks(16)][g(4)][ct(16)][lane(64)][8 shorts]
__global__ void k_wpack(const float* __restrict__ w_ih, const float* __restrict__ w_hh,
                        short* __restrict__ wp_hi, short* __restrict__ wp_lo){
  int idx = blockIdx.x*256 + threadIdx.x;       // 65536 fragment-octets
  int lane = idx & 63;
  int rest = idx >> 6;
  int ct = rest & 15; rest >>= 4;
  int g  = rest & 3;
  int ks = rest >> 2;
  int col = ct*16 + (lane & 15);
  int kb  = ks*32 + (lane >> 4)*8;
  short hi[8], lo[8];
  #pragma unroll
  for (int j = 0; j < 8; ++j){
    int k = kb + j;
    float v;
    if      (g == 0) v = (k < 256) ? w_ih[col*HH + k]        : w_hh[col*HH + k - 256];
    else if (g == 1) v = (k < 256) ? w_ih[(256+col)*HH + k]  : w_hh[(256+col)*HH + k - 256];
    else if (g == 2) v = (k < 256) ? w_ih[(512+col)*HH + k]  : 0.0f;
    else             v = (k < 256) ? 0.0f                    : w_hh[(512+col)*HH + k - 256];
    unsigned short h = f2bf(v);
    hi[j] = (short)h;
    lo[j] = (short)f2bf(v - bf2f(h));
  }
  *(short8v*)&wp_hi[(size_t)idx*8] = *(short8v*)hi;
  *(short8v*)&wp_lo[(size_t)idx*8] = *(short8v*)lo;
}

// ---------------- THE persistent step kernel ----------------
// 256 blocks x 256 threads, all co-resident (1/CU). Per step:
//  A: ax (CSR gather) + t (table lerp) for nodes [b*16, b*16+16)  -> tbuf
//  B: MFMA GRU tile rows [rb*64..+64) x h-cols [cb*64..+64)       -> h_nxt
//  C: pred dot for rows [b*16..+16)                               -> out, ring
__global__ __launch_bounds__(256) void k_steps(
    const int* __restrict__ rowst, const int* __restrict__ csr_src,
    const float* __restrict__ csr_cf, const float* __restrict__ deg,
    float* __restrict__ ring, const float* __restrict__ tab,
    const float* __restrict__ ta_b, float* __restrict__ tbuf,
    float* __restrict__ hA, float* __restrict__ hB,
    const short* __restrict__ wp_hi, const short* __restrict__ wp_lo,
    const float* __restrict__ b_ih, const float* __restrict__ b_hh,
    const float* __restrict__ out_w, const float* __restrict__ out_b,
    float* __restrict__ out, int* bar_cnt, int* bar_gen){

  __shared__ __align__(16) union SMem {
    struct { int sidx[16][12]; float sfrac[16][12]; } a;
    struct { short Ah[2][64][4][8]; short Al[2][64][4][8]; } b;   // 16 KB
  } sm;

  const int tid  = threadIdx.x;
  const int b    = blockIdx.x;
  const int nb   = gridDim.x;
  const int wv   = tid >> 6, lane = tid & 63;
  // phase-B coords
  const int rb = b >> 2, cb = b & 3;
  const int m0 = rb*64;
  const int ct4 = cb*4;
  const int a_row = wv*16 + (lane & 15);
  const int a_oct = lane >> 4;
  const int st_row = tid >> 2;        // staging: row 0..63
  const int st_oct = tid & 3;         // staging: k-oct 0..3
  // phase-A coords
  const int n0 = b*16;

  for (int s = 0; s < PP; ++s){
    const float* hc  = (s & 1) ? hB : hA;
    float*       hnb = (s & 1) ? hA : hB;

    // ---------------- phase A: ax + t ----------------
    if (tid < 192){
      int r = tid/12, w = tid - r*12;
      int node = n0 + r;
      int ph = s + w; if (ph >= WW) ph -= WW;
      float dv = 1.0f/sqrtf(deg[node] + 1.0f);
      float acc0 = dv*dv*ring[node*WW + ph];
      int e1 = rowst[node+1];
      for (int e = rowst[node]; e < e1; ++e)
        acc0 += csr_cf[e]*ring[csr_src[e]*WW + ph];
      float u = (acc0 + TA) * ((float)TS/(2.0f*TA));
      u = fminf(fmaxf(u, 0.0f), (float)TS - 0.0005f);
      int i = (int)u;
      sm.a.sidx[r][w] = i;
      sm.a.sfrac[r][w] = u - (float)i;
    }
    __syncthreads();
    {
      float tb = ta_b[tid];
      for (int r = 0; r < 16; ++r){
        float acc0 = tb;
        #pragma unroll
        for (int w = 0; w < 12; ++w){
          const float* pj = tab + ((size_t)w*(TS+1) + sm.a.sidx[r][w])*HH + tid;
          float v0 = pj[0], v1 = pj[HH];
          acc0 += v0 + sm.a.sfrac[r][w]*(v1 - v0);
        }
        tbuf[(size_t)(n0+r)*HH + tid] = acc0 > 0.0f ? acc0 : 0.0f;
      }
    }
    gbar(bar_cnt, bar_gen, nb);

    // ---------------- phase B: MFMA GRU ----------------
    {
      const float* tb_row = tbuf + (size_t)(m0 + st_row)*HH + st_oct*8;
      const float* hc_row = hc   + (size_t)(m0 + st_row)*HH + st_oct*8;

      f32x4 acc[4][4];
      #pragma unroll
      for (int g = 0; g < 4; ++g)
        #pragma unroll
        for (int c = 0; c < 4; ++c) acc[g][c] = (f32x4){0.f,0.f,0.f,0.f};

      // prologue: stage ks=0 into buf 0
      {
        float4 x0 = *(const float4*)(tb_row);
        float4 x1 = *(const float4*)(tb_row + 4);
        cvt8(x0, x1, (short8v*)&sm.b.Ah[0][st_row][st_oct][0],
                     (short8v*)&sm.b.Al[0][st_row][st_oct][0]);
      }
      __syncthreads();

#define GRU_KS(KS, G2, HAVENEXT, SRCN)                                            \
  {                                                                               \
    const int cur = (KS) & 1, nxt = cur ^ 1;                                      \
    short8v ah = *(short8v*)&sm.b.Ah[cur][a_row][a_oct][0];                       \
    short8v al = *(short8v*)&sm.b.Al[cur][a_row][a_oct][0];                       \
    float4 x0, x1;                                                                \
    if (HAVENEXT){ x0 = *(const float4*)(SRCN); x1 = *(const float4*)((SRCN)+4);} \
    _Pragma("unroll")                                                             \
    for (int c2 = 0; c2 < 4; ++c2){                                               \
      const size_t fb = (((size_t)(KS)*4)*16 + (size_t)(ct4 + c2))*64 + lane;     \
      short8v b0h = *(const short8v*)&wp_hi[(fb + (size_t)0*16*64)*8];            \
      short8v b0l = *(const short8v*)&wp_lo[(fb + (size_t)0*16*64)*8];            \
      short8v b1h = *(const short8v*)&wp_hi[(fb + (size_t)1*16*64)*8];            \
      short8v b1l = *(const short8v*)&wp_lo[(fb + (size_t)1*16*64)*8];            \
      short8v b2h = *(const short8v*)&wp_hi[(fb + (size_t)(G2)*16*64)*8];         \
      short8v b2l = *(const short8v*)&wp_lo[(fb + (size_t)(G2)*16*64)*8];         \
      acc[0][c2] = __builtin_amdgcn_mfma_f32_16x16x32_bf16(ah, b0h, acc[0][c2], 0,0,0); \
      acc[0][c2] = __builtin_amdgcn_mfma_f32_16x16x32_bf16(al, b0h, acc[0][c2], 0,0,0); \
      acc[0][c2] = __builtin_amdgcn_mfma_f32_16x16x32_bf16(ah, b0l, acc[0][c2], 0,0,0); \
      acc[1][c2] = __builtin_amdgcn_mfma_f32_16x16x32_bf16(ah, b1h, acc[1][c2], 0,0,0); \
      acc[1][c2] = __builtin_amdgcn_mfma_f32_16x16x32_bf16(al, b1h, acc[1][c2], 0,0,0); \
      acc[1][c2] = __builtin_amdgcn_mfma_f32_16x16x32_bf16(ah, b1l, acc[1][c2], 0,0,0); \
      acc[G2][c2] = __builtin_amdgcn_mfma_f32_16x16x32_bf16(ah, b2h, acc[G2][c2], 0,0,0); \
      acc[G2][c2] = __builtin_amdgcn_mfma_f32_16x16x32_bf16(al, b2h, acc[G2][c2], 0,0,0); \
      acc[G2][c2] = __builtin_amdgcn_mfma_f32_16x16x32_bf16(ah, b2l, acc[G2][c2], 0,0,0); \
    }                                                                             \
    if (HAVENEXT){                                                                \
      cvt8(x0, x1, (short8v*)&sm.b.Ah[nxt][st_row][st_oct][0],                    \
                   (short8v*)&sm.b.Al[nxt][st_row][st_oct][0]);                   \
    }                                                                             \
    __syncthreads();                                                              \
  }

      GRU_KS(0, 2, 1, tb_row + 32)
      GRU_KS(1, 2, 1, tb_row + 64)
      GRU_KS(2, 2, 1, tb_row + 96)
      GRU_KS(3, 2, 1, tb_row + 128)
      GRU_KS(4, 2, 1, tb_row + 160)
      GRU_KS(5, 2, 1, tb_row + 192)
      GRU_KS(6, 2, 1, tb_row + 224)
      GRU_KS(7, 2, 1, hc_row)
      GRU_KS(8, 3, 1, hc_row + 32)
      GRU_KS(9, 3, 1, hc_row + 64)
      GRU_KS(10, 3, 1, hc_row + 96)
      GRU_KS(11, 3, 1, hc_row + 128)
      GRU_KS(12, 3, 1, hc_row + 160)
      GRU_KS(13, 3, 1, hc_row + 192)
      GRU_KS(14, 3, 1, hc_row + 224)
      GRU_KS(15, 3, 0, hc_row)
#undef GRU_KS

      // epilogue: gates + h'
      int row_base = m0 + wv*16 + ((lane >> 4) << 2);
      int col_lane = cb*64 + (lane & 15);
      #pragma unroll
      for (int c2 = 0; c2 < 4; ++c2){
        int col = col_lane + c2*16;
        float br  = b_ih[col]        + b_hh[col];
        float bz  = b_ih[col + HH]   + b_hh[col + HH];
        float bxn = b_ih[col + 2*HH];
        float bhn = b_hh[col + 2*HH];
        #pragma unroll
        for (int q = 0; q < 4; ++q){
          int row = row_base + q;
          float r = fast_sigmoid(acc[0][c2][q] + br);
          float z = fast_sigmoid(acc[1][c2][q] + bz);
          float n = fast_tanh(acc[2][c2][q] + bxn + r*(acc[3][c2][q] + bhn));
          float hv = hc[(size_t)row*HH + col];
          hnb[(size_t)row*HH + col] = (1.0f - z)*n + z*hv;
        }
      }
    }
    gbar(bar_cnt, bar_gen, nb);

    // ---------------- phase C: pred ----------------
    {
      int row = n0 + wv*4 + (lane >> 4);
      int c0 = (lane & 15)*16;
      const float* hr = hnb + (size_t)row*HH + c0;
      float sacc = 0.0f;
      #pragma unroll
      for (int j = 0; j < 4; ++j){
        float4 hv = *(const float4*)(hr + j*4);
        float4 w4 = *(const float4*)(out_w + c0 + j*4);
        sacc += hv.x*w4.x + hv.y*w4.y + hv.z*w4.z + hv.w*w4.w;
      }
      sacc += __shfl_xor(sacc, 1, 64);
      sacc += __shfl_xor(sacc, 2, 64);
      sacc += __shfl_xor(sacc, 4, 64);
      sacc += __shfl_xor(sacc, 8, 64);
      if ((lane & 15) == 0){
        float pv = sacc + out_b[0];
        out[(size_t)row*PP + s] = pv;
        ring[(size_t)row*WW + s] = pv;   // slot s is the one rotated out
      }
    }
    gbar(bar_cnt, bar_gen, nb);
  }
}

// ---------------- launcher ----------------

extern "C" void kernel_launch(void* const* d_in, const int* in_sizes, int n_in,
                              void* d_out, int out_size, void* d_ws, size_t ws_size,
                              hipStream_t stream){
  const float* x     = (const float*)d_in[0];
  const int*   ei    = (const int*)  d_in[1];
  const float* ew    = (const float*)d_in[2];
  const float* gcn_w = (const float*)d_in[3];
  const float* ta_w  = (const float*)d_in[4];
  const float* ta_b  = (const float*)d_in[5];
  const float* w_ih  = (const float*)d_in[6];
  const float* w_hh  = (const float*)d_in[7];
  const float* b_ih  = (const float*)d_in[8];
  const float* b_hh  = (const float*)d_in[9];
  const float* out_w = (const float*)d_in[10];
  const float* out_b = (const float*)d_in[11];
  float* out = (float*)d_out;

  // tab occupies the front of ws; setup-only buffers (hash + edge temps,
  // 4.5 MB) ALIAS into tab's 12.6 MB region — dead before k_tab runs.
  char* base = (char*)d_ws;
  float* tab = (float*)base;                               // 12*(TS+1)*HH*4 = 12.6 MB
  char* p = base;
  int*   keys    = (int*)p;   p += (size_t)HS*4;           // |
  int*   midx    = (int*)p;   p += (size_t)HS*4;           // | setup-only,
  int*   wsrc    = (int*)p;   p += (size_t)EE*4;           // | aliased inside tab
  int*   wdst    = (int*)p;   p += (size_t)EE*4;           // |
  float* wwt     = (float*)p; p += (size_t)EE*4;           // |
  p = base + (size_t)12*(TS+1)*HH*4;                       // end of tab
  int*   csr_src = (int*)p;   p += (size_t)EE*4;
  float* csr_cf  = (float*)p; p += (size_t)EE*4;
  float* deg     = (float*)p; p += (size_t)NN*4;
  int*   cnt     = (int*)p;   p += (size_t)NN*4;
  int*   fill    = (int*)p;   p += (size_t)NN*4;
  int*   rowst   = (int*)p;   p += (size_t)(NN+64)*4;
  int*   count   = (int*)p;   p += 256;
  int*   bar_cnt = (int*)p;   p += 256;
  int*   bar_gen = (int*)p;   p += 256;
  float* ring    = (float*)p; p += (size_t)NN*WW*4;
  float* tbuf    = (float*)p; p += (size_t)NN*HH*4;
  float* hA      = (float*)p; p += (size_t)NN*HH*4;
  float* hB      = (float*)p; p += (size_t)NN*HH*4;
  short* wp_hi   = (short*)p; p += (size_t)16*4*16*64*8*2; // 1 MB
  short* wp_lo   = (short*)p; p += (size_t)16*4*16*64*8*2; // 1 MB

  k_init   <<<(NN*HH)/256, 256, 0, stream>>>(x, keys, midx, deg, cnt, ring, hA,
                                             count, bar_cnt, bar_gen);
  k_insert <<<EE/256, 256, 0, stream>>>(ei, keys, midx);
  k_compact<<<EE/256, 256, 0, stream>>>(ei, ew, keys, midx, wsrc, wdst, wwt, deg, cnt, count);
  k_scan   <<<1, 1024, 0, stream>>>(cnt, rowst, fill);
  k_scatter<<<EE/256, 256, 0, stream>>>(wsrc, wdst, wwt, deg, fill, csr_src, csr_cf, count);
  k_wpack  <<<256, 256, 0, stream>>>(w_ih, w_hh, wp_hi, wp_lo);
  // after k_scatter the aliased setup buffers are dead; build the table over them
  k_tab    <<<dim3(HH/64, (TS+64)/64, WW), 256, 0, stream>>>(gcn_w, ta_w, tab);

  k_steps  <<<NBLK, 256, 0, stream>>>(rowst, csr_src, csr_cf, deg, ring, tab,
                                      ta_b, tbuf, hA, hB, wp_hi, wp_lo,
                                      b_ih, b_hh, out_w, out_b, out,
                                      bar_cnt, bar_gen);
}

// Round 5
// 612.643 us; speedup vs baseline: 5.3635x; 5.3635x over previous
//
#include <hip/hip_runtime.h>
#include <math.h>

#define NN 4096
#define WW 12
#define HH 256
#define PP 10
#define EE 131072
#define HS 262144
#define HMASK (HS-1)
#define TS 1024          // table intervals (1025 sample points)
#define TA 12.0f         // table half-domain: a in [-TA, TA]
#define RS 22            // ring stride: 12 init cols + 10 pred cols (append, no overwrite)

typedef __attribute__((ext_vector_type(8))) short short8v;   // 8 x bf16 (A/B frag)
typedef __attribute__((ext_vector_type(4))) float f32x4;     // C/D frag

__device__ __forceinline__ float fast_tanh(float x){
  float e = __expf(2.0f*x);
  return 1.0f - 2.0f/(e+1.0f);   // exact identity (e^2x-1)/(e^2x+1)
}
__device__ __forceinline__ float fast_sigmoid(float x){
  return 1.0f/(1.0f+__expf(-x));
}
__device__ __forceinline__ unsigned short f2bf(float f){     // RNE fp32->bf16
  union{float f; unsigned u;} v; v.f = f;
  unsigned r = v.u + 0x7FFF + ((v.u>>16)&1);
  return (unsigned short)(r>>16);
}
__device__ __forceinline__ float bf2f(unsigned short h){
  union{unsigned u; float f;} v; v.u = ((unsigned)h)<<16; return v.f;
}
__device__ __forceinline__ void cvt8(const float4 x0, const float4 x1,
                                     short8v* oh, short8v* ol){
  float f[8] = {x0.x,x0.y,x0.z,x0.w,x1.x,x1.y,x1.z,x1.w};
  short h8[8], l8[8];
  #pragma unroll
  for (int j = 0; j < 8; ++j){
    unsigned short hh_ = f2bf(f[j]);
    h8[j] = (short)hh_;
    l8[j] = (short)f2bf(f[j] - bf2f(hh_));
  }
  *oh = *(short8v*)h8; *ol = *(short8v*)l8;
}

// ---------------- setup kernels ----------------

__global__ void k_init(const float* __restrict__ x, int* keys, int* midx,
                       float* deg, int* cnt, float* ring, float* hA, int* count){
  int i = blockIdx.x*256 + threadIdx.x;
  if (i < HS){ keys[i] = -1; midx[i] = -1; }
  if (i < NN){ deg[i] = 0.0f; cnt[i] = 0; }
  if (i < NN*WW){ int n = i/WW, w = i - n*WW; ring[n*RS + w] = x[i]; }
  if (i < NN*HH) hA[i] = 0.0f;
  if (i == 0) *count = 0;
}

// dedupe: numpy fancy assignment => last (max-index) edge wins per (src,dst)
__global__ void k_insert(const int* __restrict__ ei, int* keys, int* midx){
  int e = blockIdx.x*256 + threadIdx.x;
  if (e >= EE) return;
  int key = ei[e]*NN + ei[EE+e];
  unsigned h = (((unsigned)key)*2654435761u >> 14) & HMASK;
  for(;;){
    int k = keys[h];
    if (k == key){ atomicMax(&midx[h], e); return; }
    if (k == -1){
      int old = atomicCAS(&keys[h], -1, key);
      if (old == -1 || old == key){ atomicMax(&midx[h], e); return; }
    }
    h = (h+1) & HMASK;
  }
}

__global__ void k_compact(const int* __restrict__ ei, const float* __restrict__ ew,
                          const int* __restrict__ keys, const int* __restrict__ midx,
                          int* wsrc, int* wdst, float* wwt,
                          float* deg, int* cnt, int* count){
  int e = blockIdx.x*256 + threadIdx.x;
  if (e >= EE) return;
  int src = ei[e], dst = ei[EE+e];
  int key = src*NN + dst;
  unsigned h = (((unsigned)key)*2654435761u >> 14) & HMASK;
  while (keys[h] != key) h = (h+1) & HMASK;
  if (midx[h] == e){            // this edge is the winner for (src,dst)
    int p = atomicAdd(count, 1);
    wsrc[p] = src; wdst[p] = dst; wwt[p] = ew[e];
    atomicAdd(&deg[src], ew[e]);   // deg = row-sum of deduped adj (self-loop +1 later)
    atomicAdd(&cnt[dst], 1);       // CSR histogram keyed by dst (L uses adj^T)
  }
}

__global__ __launch_bounds__(1024) void k_scan(const int* __restrict__ cnt,
                                               int* row_start, int* fill){
  __shared__ int sd[NN];
  int tid = threadIdx.x;
  for (int i = tid; i < NN; i += 1024) sd[i] = cnt[i];
  __syncthreads();
  for (int off = 1; off < NN; off <<= 1){
    int v[4];
    #pragma unroll
    for (int r = 0; r < 4; ++r){
      int i = tid + r*1024;
      v[r] = (i >= off) ? sd[i-off] : 0;
    }
    __syncthreads();
    #pragma unroll
    for (int r = 0; r < 4; ++r) sd[tid + r*1024] += v[r];
    __syncthreads();
  }
  for (int i = tid; i < NN; i += 1024){
    int incl = sd[i];
    row_start[i+1] = incl;
    fill[i] = incl - cnt[i];   // exclusive prefix = scatter cursor
  }
  if (tid == 0) row_start[0] = 0;
}

// scatter + inline coef = wwt * d[src] * d[dst], d = 1/sqrt(deg+1)
__global__ void k_scatter(const int* __restrict__ wsrc, const int* __restrict__ wdst,
                          const float* __restrict__ wwt, const float* __restrict__ deg,
                          int* fill, int* csr_src, float* csr_cf,
                          const int* __restrict__ count){
  int p = blockIdx.x*256 + threadIdx.x;
  if (p >= *count) return;
  int s = wsrc[p], d = wdst[p];
  float c = wwt[p] * (1.0f/sqrtf(deg[s]+1.0f)) * (1.0f/sqrtf(deg[d]+1.0f));
  int pos = atomicAdd(&fill[d], 1);
  csr_src[pos] = s;
  csr_cf[pos] = c;
}

// table build: tab[w][s][h] = sum_c tanh(a_s*gw[c]) * ta_w[w*256+c, h]
__global__ __launch_bounds__(256) void k_tab(const float* __restrict__ gcn_w,
                                             const float* __restrict__ ta_w,
                                             float* __restrict__ tab){
  __shared__ float As[32][64];
  __shared__ float Bs[32][64];
  __shared__ float gws[256];
  int tid = threadIdx.x;
  int n0 = blockIdx.x*64;        // h tile
  int m0 = blockIdx.y*64;        // sample tile
  int w  = blockIdx.z;
  gws[tid] = gcn_w[tid];
  __syncthreads();
  float acc[4][4] = {};
  int tm = tid >> 4, tn = tid & 15;
  const float astep = 2.0f*TA/TS;
  for (int k0 = 0; k0 < 256; k0 += 32){
    #pragma unroll
    for (int r = 0; r < 2; ++r){
      int f = tid + r*256;
      int kk = f >> 4, n4 = (f & 15)*4;
      *(float4*)&Bs[kk][n4] = *(const float4*)&ta_w[(w*256 + k0+kk)*HH + n0 + n4];
    }
    {
      int kk = tid >> 3;
      int mb = (tid & 7)*8;
      float gw = gws[k0 + kk];
      #pragma unroll
      for (int i2 = 0; i2 < 8; ++i2){
        float a = -TA + (float)(m0 + mb + i2)*astep;
        As[kk][mb+i2] = fast_tanh(a*gw);
      }
    }
    __syncthreads();
    #pragma unroll
    for (int kk = 0; kk < 32; ++kk){
      float4 a4 = *(float4*)&As[kk][tm*4];
      float4 b4 = *(float4*)&Bs[kk][tn*4];
      float a[4] = {a4.x,a4.y,a4.z,a4.w};
      float b[4] = {b4.x,b4.y,b4.z,b4.w};
      #pragma unroll
      for (int i = 0; i < 4; ++i)
        #pragma unroll
        for (int j = 0; j < 4; ++j)
          acc[i][j] = fmaf(a[i], b[j], acc[i][j]);
    }
    __syncthreads();
  }
  #pragma unroll
  for (int i = 0; i < 4; ++i){
    int row = m0 + tm*4 + i;
    if (row <= TS){
      #pragma unroll
      for (int j = 0; j < 4; ++j)
        tab[((size_t)w*(TS+1) + row)*HH + n0 + tn*4 + j] = acc[i][j];
    }
  }
}

// pack GRU weights into MFMA B-fragment order, bf16 hi/lo planes (run once).
// groups g: 0=r, 1=z, 2=xn (K 0..255), 3=hn (K 256..511).
// layout: [ks(16)][g(4)][ct(16)][lane(64)][8 shorts]
__global__ void k_wpack(const float* __restrict__ w_ih, const float* __restrict__ w_hh,
                        short* __restrict__ wp_hi, short* __restrict__ wp_lo){
  int idx = blockIdx.x*256 + threadIdx.x;       // 65536 fragment-octets
  int lane = idx & 63;
  int rest = idx >> 6;
  int ct = rest & 15; rest >>= 4;
  int g  = rest & 3;
  int ks = rest >> 2;
  int col = ct*16 + (lane & 15);
  int kb  = ks*32 + (lane >> 4)*8;
  short hi[8], lo[8];
  #pragma unroll
  for (int j = 0; j < 8; ++j){
    int k = kb + j;
    float v;
    if      (g == 0) v = (k < 256) ? w_ih[col*HH + k]        : w_hh[col*HH + k - 256];
    else if (g == 1) v = (k < 256) ? w_ih[(256+col)*HH + k]  : w_hh[(256+col)*HH + k - 256];
    else if (g == 2) v = (k < 256) ? w_ih[(512+col)*HH + k]  : 0.0f;
    else             v = (k < 256) ? 0.0f                    : w_hh[(512+col)*HH + k - 256];
    unsigned short h = f2bf(v);
    hi[j] = (short)h;
    lo[j] = (short)f2bf(v - bf2f(h));
  }
  *(short8v*)&wp_hi[(size_t)idx*8] = *(short8v*)hi;
  *(short8v*)&wp_lo[(size_t)idx*8] = *(short8v*)lo;
}

// ---------------- the per-step kernel ----------------
// One dispatch per horizon step; 256 blocks x 256 threads; block owns nodes
// [16b, 16b+16) END-TO-END. No intra-dispatch cross-block dependencies:
//  A: CSR gather + table lerp -> t (LDS)          [reads ring cols s..s+11]
//  B: GRU MFMA 16 rows x 256 cols, K=512 from LDS t|hc -> h' (global + LDS)
//  C: pred dot from LDS h' -> out col s, ring col 12+s
__global__ __launch_bounds__(256) void k_step(
    const int* __restrict__ rowst, const int* __restrict__ csr_src,
    const float* __restrict__ csr_cf, const float* __restrict__ deg,
    float* __restrict__ ring, const float* __restrict__ tab,
    const float* __restrict__ ta_b,
    const float* __restrict__ hc, float* __restrict__ hnb,
    const short* __restrict__ wp_hi, const short* __restrict__ wp_lo,
    const float* __restrict__ b_ih, const float* __restrict__ b_hh,
    const float* __restrict__ out_w, const float* __restrict__ out_b,
    float* __restrict__ out, int s){

  // 260-float row stride: stride%32 = 4 banks -> 2-way aliasing (free) on
  // the 16-row column-slice ds_reads; 1040 B keeps 16-B alignment.
  __shared__ __align__(16) float t_pad[16][260];
  __shared__ __align__(16) float h_pad[16][260];
  __shared__ int   sidx[16][12];
  __shared__ float sfrac[16][12];

  const int tid = threadIdx.x;
  const int n0 = blockIdx.x*16;
  const int wv = tid >> 6, lane = tid & 63;

  // ---- stage hc -> LDS, CSR gather -> sidx/sfrac ----
  {
    int row = tid >> 4, c0 = (tid & 15)*16;
    const float* hr = hc + (size_t)(n0+row)*HH + c0;
    float4 v0 = *(const float4*)(hr);
    float4 v1 = *(const float4*)(hr+4);
    float4 v2 = *(const float4*)(hr+8);
    float4 v3 = *(const float4*)(hr+12);
    *(float4*)&h_pad[row][c0]    = v0;
    *(float4*)&h_pad[row][c0+4]  = v1;
    *(float4*)&h_pad[row][c0+8]  = v2;
    *(float4*)&h_pad[row][c0+12] = v3;
  }
  if (tid < 192){
    int r = tid/12, w = tid - r*12;
    int node = n0 + r;
    float dv = 1.0f/sqrtf(deg[node] + 1.0f);
    float acc0 = dv*dv*ring[(size_t)node*RS + s + w];
    int e1 = rowst[node+1];
    for (int e = rowst[node]; e < e1; ++e)
      acc0 += csr_cf[e]*ring[(size_t)csr_src[e]*RS + s + w];
    float u = (acc0 + TA) * ((float)TS/(2.0f*TA));
    u = fminf(fmaxf(u, 0.0f), (float)TS - 0.0005f);
    int i = (int)u;
    sidx[r][w] = i;
    sfrac[r][w] = u - (float)i;
  }
  __syncthreads();

  // ---- table lerp -> t (LDS) ----
  {
    float tb = ta_b[tid];
    #pragma unroll
    for (int r = 0; r < 16; ++r){
      float acc0 = tb;
      #pragma unroll
      for (int w = 0; w < 12; ++w){
        const float* pj = tab + ((size_t)w*(TS+1) + sidx[r][w])*HH + tid;
        float v0 = pj[0], v1 = pj[HH];
        acc0 += v0 + sfrac[r][w]*(v1 - v0);
      }
      t_pad[r][tid] = acc0 > 0.0f ? acc0 : 0.0f;
    }
  }
  __syncthreads();

  // ---- GRU MFMA: 16 rows x (wave's 64 cols), K=512 ----
  f32x4 acc[4][4];
  #pragma unroll
  for (int g = 0; g < 4; ++g)
    #pragma unroll
    for (int c = 0; c < 4; ++c) acc[g][c] = (f32x4){0.f,0.f,0.f,0.f};

  const int a_row = lane & 15, a_oct = lane >> 4;

  #pragma unroll
  for (int ks = 0; ks < 16; ++ks){
    const float* ap = (ks < 8) ? &t_pad[a_row][ks*32 + a_oct*8]
                               : &h_pad[a_row][(ks-8)*32 + a_oct*8];
    float4 x0 = *(const float4*)ap;
    float4 x1 = *(const float4*)(ap+4);
    short8v ah, al;
    cvt8(x0, x1, &ah, &al);
    const int G2 = (ks < 8) ? 2 : 3;
    #pragma unroll
    for (int c2 = 0; c2 < 4; ++c2){
      const int ct = wv*4 + c2;
      const size_t fb = (((size_t)ks*4)*16 + (size_t)ct)*64 + lane;
      short8v b0h = *(const short8v*)&wp_hi[(fb + (size_t)0*16*64)*8];
      short8v b0l = *(const short8v*)&wp_lo[(fb + (size_t)0*16*64)*8];
      short8v b1h = *(const short8v*)&wp_hi[(fb + (size_t)1*16*64)*8];
      short8v b1l = *(const short8v*)&wp_lo[(fb + (size_t)1*16*64)*8];
      short8v b2h = *(const short8v*)&wp_hi[(fb + (size_t)G2*16*64)*8];
      short8v b2l = *(const short8v*)&wp_lo[(fb + (size_t)G2*16*64)*8];
      acc[0][c2]  = __builtin_amdgcn_mfma_f32_16x16x32_bf16(ah, b0h, acc[0][c2], 0,0,0);
      acc[0][c2]  = __builtin_amdgcn_mfma_f32_16x16x32_bf16(al, b0h, acc[0][c2], 0,0,0);
      acc[0][c2]  = __builtin_amdgcn_mfma_f32_16x16x32_bf16(ah, b0l, acc[0][c2], 0,0,0);
      acc[1][c2]  = __builtin_amdgcn_mfma_f32_16x16x32_bf16(ah, b1h, acc[1][c2], 0,0,0);
      acc[1][c2]  = __builtin_amdgcn_mfma_f32_16x16x32_bf16(al, b1h, acc[1][c2], 0,0,0);
      acc[1][c2]  = __builtin_amdgcn_mfma_f32_16x16x32_bf16(ah, b1l, acc[1][c2], 0,0,0);
      acc[G2][c2] = __builtin_amdgcn_mfma_f32_16x16x32_bf16(ah, b2h, acc[G2][c2], 0,0,0);
      acc[G2][c2] = __builtin_amdgcn_mfma_f32_16x16x32_bf16(al, b2h, acc[G2][c2], 0,0,0);
      acc[G2][c2] = __builtin_amdgcn_mfma_f32_16x16x32_bf16(ah, b2l, acc[G2][c2], 0,0,0);
    }
  }
  __syncthreads();   // everyone done reading t_pad before epilogue overwrites it

  // ---- epilogue: gates + h' -> global hnb + LDS (t_pad reused as h') ----
  {
    const int erow = (lane >> 4)*4;
    const int ecl  = lane & 15;
    #pragma unroll
    for (int c2 = 0; c2 < 4; ++c2){
      int col = wv*64 + c2*16 + ecl;
      float br  = b_ih[col]        + b_hh[col];
      float bz  = b_ih[col + HH]   + b_hh[col + HH];
      float bxn = b_ih[col + 2*HH];
      float bhn = b_hh[col + 2*HH];
      #pragma unroll
      for (int q = 0; q < 4; ++q){
        int row = erow + q;
        float r = fast_sigmoid(acc[0][c2][q] + br);
        float z = fast_sigmoid(acc[1][c2][q] + bz);
        float n = fast_tanh(acc[2][c2][q] + bxn + r*(acc[3][c2][q] + bhn));
        float hv = h_pad[row][col];
        float hp = (1.0f - z)*n + z*hv;
        hnb[(size_t)(n0+row)*HH + col] = hp;
        t_pad[row][col] = hp;
      }
    }
  }
  __syncthreads();

  // ---- pred: h' . out_w + out_b -> out col s, ring col 12+s ----
  {
    int prow = wv*4 + (lane >> 4);
    int pc0  = (lane & 15)*16;
    float sacc = 0.0f;
    #pragma unroll
    for (int j = 0; j < 4; ++j){
      float4 hv = *(const float4*)&t_pad[prow][pc0 + j*4];
      float4 w4 = *(const float4*)(out_w + pc0 + j*4);
      sacc += hv.x*w4.x + hv.y*w4.y + hv.z*w4.z + hv.w*w4.w;
    }
    sacc += __shfl_xor(sacc, 1, 64);
    sacc += __shfl_xor(sacc, 2, 64);
    sacc += __shfl_xor(sacc, 4, 64);
    sacc += __shfl_xor(sacc, 8, 64);
    if ((lane & 15) == 0){
      float pv = sacc + out_b[0];
      out[(size_t)(n0+prow)*PP + s] = pv;
      ring[(size_t)(n0+prow)*RS + 12 + s] = pv;
    }
  }
}

// ---------------- launcher ----------------

extern "C" void kernel_launch(void* const* d_in, const int* in_sizes, int n_in,
                              void* d_out, int out_size, void* d_ws, size_t ws_size,
                              hipStream_t stream){
  const float* x     = (const float*)d_in[0];
  const int*   ei    = (const int*)  d_in[1];
  const float* ew    = (const float*)d_in[2];
  const float* gcn_w = (const float*)d_in[3];
  const float* ta_w  = (const float*)d_in[4];
  const float* ta_b  = (const float*)d_in[5];
  const float* w_ih  = (const float*)d_in[6];
  const float* w_hh  = (const float*)d_in[7];
  const float* b_ih  = (const float*)d_in[8];
  const float* b_hh  = (const float*)d_in[9];
  const float* out_w = (const float*)d_in[10];
  const float* out_b = (const float*)d_in[11];
  float* out = (float*)d_out;

  // tab occupies the front of ws; setup-only buffers (hash + edge temps,
  // 4.5 MB) ALIAS into tab's 12.6 MB region — dead before k_tab runs.
  char* base = (char*)d_ws;
  float* tab = (float*)base;                               // 12*(TS+1)*HH*4 = 12.6 MB
  char* p = base;
  int*   keys    = (int*)p;   p += (size_t)HS*4;           // |
  int*   midx    = (int*)p;   p += (size_t)HS*4;           // | setup-only,
  int*   wsrc    = (int*)p;   p += (size_t)EE*4;           // | aliased inside tab
  int*   wdst    = (int*)p;   p += (size_t)EE*4;           // |
  float* wwt     = (float*)p; p += (size_t)EE*4;           // |
  p = base + (size_t)12*(TS+1)*HH*4;                       // end of tab
  int*   csr_src = (int*)p;   p += (size_t)EE*4;
  float* csr_cf  = (float*)p; p += (size_t)EE*4;
  float* deg     = (float*)p; p += (size_t)NN*4;
  int*   cnt     = (int*)p;   p += (size_t)NN*4;
  int*   fill    = (int*)p;   p += (size_t)NN*4;
  int*   rowst   = (int*)p;   p += (size_t)(NN+64)*4;
  int*   count   = (int*)p;   p += 256;
  float* ring    = (float*)p; p += (size_t)NN*RS*4;
  float* hA      = (float*)p; p += (size_t)NN*HH*4;
  float* hB      = (float*)p; p += (size_t)NN*HH*4;
  short* wp_hi   = (short*)p; p += (size_t)16*4*16*64*8*2; // 1 MB
  short* wp_lo   = (short*)p; p += (size_t)16*4*16*64*8*2; // 1 MB

  k_init   <<<(NN*HH)/256, 256, 0, stream>>>(x, keys, midx, deg, cnt, ring, hA, count);
  k_insert <<<EE/256, 256, 0, stream>>>(ei, keys, midx);
  k_compact<<<EE/256, 256, 0, stream>>>(ei, ew, keys, midx, wsrc, wdst, wwt, deg, cnt, count);
  k_scan   <<<1, 1024, 0, stream>>>(cnt, rowst, fill);
  k_scatter<<<EE/256, 256, 0, stream>>>(wsrc, wdst, wwt, deg, fill, csr_src, csr_cf, count);
  k_wpack  <<<256, 256, 0, stream>>>(w_ih, w_hh, wp_hi, wp_lo);
  // after k_scatter the aliased setup buffers are dead; build the table over them
  k_tab    <<<dim3(HH/64, (TS+64)/64, WW), 256, 0, stream>>>(gcn_w, ta_w, tab);

  for (int s = 0; s < PP; ++s){
    const float* hc  = (s & 1) ? hB : hA;
    float*       hnb = (s & 1) ? hA : hB;
    k_step<<<NN/16, 256, 0, stream>>>(rowst, csr_src, csr_cf, deg, ring, tab,
                                      ta_b, hc, hnb, wp_hi, wp_lo,
                                      b_ih, b_hh, out_w, out_b, out, s);
  }
}

// Round 6
// 433.515 us; speedup vs baseline: 7.5796x; 1.4132x over previous
//
#include <hip/hip_runtime.h>
#include <math.h>

#define NN 4096
#define WW 12
#define HH 256
#define PP 10
#define EE 131072
#define HS 262144
#define HMASK (HS-1)
#define TS 192           // table intervals (193 sample points) -> 2.37 MB, L2-resident
#define TA 8.0f          // table half-domain: a in [-TA, TA]
#define RS 22            // ring stride: 12 init cols + 10 pred cols (append, no overwrite)

typedef __attribute__((ext_vector_type(8))) short short8v;   // 8 x bf16 (A/B frag)
typedef __attribute__((ext_vector_type(4))) float f32x4;     // C/D frag

__device__ __forceinline__ float fast_tanh(float x){
  float e = __expf(2.0f*x);
  return 1.0f - 2.0f/(e+1.0f);   // exact identity (e^2x-1)/(e^2x+1)
}
__device__ __forceinline__ float fast_sigmoid(float x){
  return 1.0f/(1.0f+__expf(-x));
}
__device__ __forceinline__ unsigned short f2bf(float f){     // RNE fp32->bf16
  union{float f; unsigned u;} v; v.f = f;
  unsigned r = v.u + 0x7FFF + ((v.u>>16)&1);
  return (unsigned short)(r>>16);
}
__device__ __forceinline__ float bf2f(unsigned short h){
  union{unsigned u; float f;} v; v.u = ((unsigned)h)<<16; return v.f;
}
__device__ __forceinline__ void cvt8(const float4 x0, const float4 x1,
                                     short8v* oh, short8v* ol){
  float f[8] = {x0.x,x0.y,x0.z,x0.w,x1.x,x1.y,x1.z,x1.w};
  short h8[8], l8[8];
  #pragma unroll
  for (int j = 0; j < 8; ++j){
    unsigned short hh_ = f2bf(f[j]);
    h8[j] = (short)hh_;
    l8[j] = (short)f2bf(f[j] - bf2f(hh_));
  }
  *oh = *(short8v*)h8; *ol = *(short8v*)l8;
}

// ---------------- setup kernels ----------------

__global__ void k_init(const float* __restrict__ x, int* keys, int* midx,
                       float* deg, int* cnt, float* ring, float* hA, int* count){
  int i = blockIdx.x*256 + threadIdx.x;
  if (i < HS){ keys[i] = -1; midx[i] = -1; }
  if (i < NN){ deg[i] = 0.0f; cnt[i] = 0; }
  if (i < NN*WW){ int n = i/WW, w = i - n*WW; ring[n*RS + w] = x[i]; }
  if (i < NN*HH) hA[i] = 0.0f;
  if (i == 0) *count = 0;
}

// dedupe: numpy fancy assignment => last (max-index) edge wins per (src,dst)
__global__ void k_insert(const int* __restrict__ ei, int* keys, int* midx){
  int e = blockIdx.x*256 + threadIdx.x;
  if (e >= EE) return;
  int key = ei[e]*NN + ei[EE+e];
  unsigned h = (((unsigned)key)*2654435761u >> 14) & HMASK;
  for(;;){
    int k = keys[h];
    if (k == key){ atomicMax(&midx[h], e); return; }
    if (k == -1){
      int old = atomicCAS(&keys[h], -1, key);
      if (old == -1 || old == key){ atomicMax(&midx[h], e); return; }
    }
    h = (h+1) & HMASK;
  }
}

__global__ void k_compact(const int* __restrict__ ei, const float* __restrict__ ew,
                          const int* __restrict__ keys, const int* __restrict__ midx,
                          int* wsrc, int* wdst, float* wwt,
                          float* deg, int* cnt, int* count){
  int e = blockIdx.x*256 + threadIdx.x;
  if (e >= EE) return;
  int src = ei[e], dst = ei[EE+e];
  int key = src*NN + dst;
  unsigned h = (((unsigned)key)*2654435761u >> 14) & HMASK;
  while (keys[h] != key) h = (h+1) & HMASK;
  if (midx[h] == e){            // this edge is the winner for (src,dst)
    int p = atomicAdd(count, 1);
    wsrc[p] = src; wdst[p] = dst; wwt[p] = ew[e];
    atomicAdd(&deg[src], ew[e]);   // deg = row-sum of deduped adj (self-loop +1 later)
    atomicAdd(&cnt[dst], 1);       // CSR histogram keyed by dst (L uses adj^T)
  }
}

__global__ __launch_bounds__(1024) void k_scan(const int* __restrict__ cnt,
                                               int* row_start, int* fill){
  __shared__ int sd[NN];
  int tid = threadIdx.x;
  for (int i = tid; i < NN; i += 1024) sd[i] = cnt[i];
  __syncthreads();
  for (int off = 1; off < NN; off <<= 1){
    int v[4];
    #pragma unroll
    for (int r = 0; r < 4; ++r){
      int i = tid + r*1024;
      v[r] = (i >= off) ? sd[i-off] : 0;
    }
    __syncthreads();
    #pragma unroll
    for (int r = 0; r < 4; ++r) sd[tid + r*1024] += v[r];
    __syncthreads();
  }
  for (int i = tid; i < NN; i += 1024){
    int incl = sd[i];
    row_start[i+1] = incl;
    fill[i] = incl - cnt[i];   // exclusive prefix = scatter cursor
  }
  if (tid == 0) row_start[0] = 0;
}

// scatter + inline coef = wwt * d[src] * d[dst], d = 1/sqrt(deg+1)
__global__ void k_scatter(const int* __restrict__ wsrc, const int* __restrict__ wdst,
                          const float* __restrict__ wwt, const float* __restrict__ deg,
                          int* fill, int* csr_src, float* csr_cf,
                          const int* __restrict__ count){
  int p = blockIdx.x*256 + threadIdx.x;
  if (p >= *count) return;
  int s = wsrc[p], d = wdst[p];
  float c = wwt[p] * (1.0f/sqrtf(deg[s]+1.0f)) * (1.0f/sqrtf(deg[d]+1.0f));
  int pos = atomicAdd(&fill[d], 1);
  csr_src[pos] = s;
  csr_cf[pos] = c;
}

// table build: tab[w][s][h] = sum_c tanh(a_s*gw[c]) * ta_w[w*256+c, h]
__global__ __launch_bounds__(256) void k_tab(const float* __restrict__ gcn_w,
                                             const float* __restrict__ ta_w,
                                             float* __restrict__ tab){
  __shared__ float As[32][64];
  __shared__ float Bs[32][64];
  __shared__ float gws[256];
  int tid = threadIdx.x;
  int n0 = blockIdx.x*64;        // h tile
  int m0 = blockIdx.y*64;        // sample tile
  int w  = blockIdx.z;
  gws[tid] = gcn_w[tid];
  __syncthreads();
  float acc[4][4] = {};
  int tm = tid >> 4, tn = tid & 15;
  const float astep = 2.0f*TA/TS;
  for (int k0 = 0; k0 < 256; k0 += 32){
    #pragma unroll
    for (int r = 0; r < 2; ++r){
      int f = tid + r*256;
      int kk = f >> 4, n4 = (f & 15)*4;
      *(float4*)&Bs[kk][n4] = *(const float4*)&ta_w[(w*256 + k0+kk)*HH + n0 + n4];
    }
    {
      int kk = tid >> 3;
      int mb = (tid & 7)*8;
      float gw = gws[k0 + kk];
      #pragma unroll
      for (int i2 = 0; i2 < 8; ++i2){
        float a = -TA + (float)(m0 + mb + i2)*astep;
        As[kk][mb+i2] = fast_tanh(a*gw);
      }
    }
    __syncthreads();
    #pragma unroll
    for (int kk = 0; kk < 32; ++kk){
      float4 a4 = *(float4*)&As[kk][tm*4];
      float4 b4 = *(float4*)&Bs[kk][tn*4];
      float a[4] = {a4.x,a4.y,a4.z,a4.w};
      float b[4] = {b4.x,b4.y,b4.z,b4.w};
      #pragma unroll
      for (int i = 0; i < 4; ++i)
        #pragma unroll
        for (int j = 0; j < 4; ++j)
          acc[i][j] = fmaf(a[i], b[j], acc[i][j]);
    }
    __syncthreads();
  }
  #pragma unroll
  for (int i = 0; i < 4; ++i){
    int row = m0 + tm*4 + i;
    if (row <= TS){
      #pragma unroll
      for (int j = 0; j < 4; ++j)
        tab[((size_t)w*(TS+1) + row)*HH + n0 + tn*4 + j] = acc[i][j];
    }
  }
}

// pack GRU weights into MFMA B-fragment order, bf16 hi/lo planes (run once).
// groups g: 0=r, 1=z, 2=xn (K 0..255), 3=hn (K 256..511).
// layout: [ks(16)][g(4)][ct(16)][lane(64)][8 shorts]
__global__ void k_wpack(const float* __restrict__ w_ih, const float* __restrict__ w_hh,
                        short* __restrict__ wp_hi, short* __restrict__ wp_lo){
  int idx = blockIdx.x*256 + threadIdx.x;       // 65536 fragment-octets
  int lane = idx & 63;
  int rest = idx >> 6;
  int ct = rest & 15; rest >>= 4;
  int g  = rest & 3;
  int ks = rest >> 2;
  int col = ct*16 + (lane & 15);
  int kb  = ks*32 + (lane >> 4)*8;
  short hi[8], lo[8];
  #pragma unroll
  for (int j = 0; j < 8; ++j){
    int k = kb + j;
    float v;
    if      (g == 0) v = (k < 256) ? w_ih[col*HH + k]        : w_hh[col*HH + k - 256];
    else if (g == 1) v = (k < 256) ? w_ih[(256+col)*HH + k]  : w_hh[(256+col)*HH + k - 256];
    else if (g == 2) v = (k < 256) ? w_ih[(512+col)*HH + k]  : 0.0f;
    else             v = (k < 256) ? 0.0f                    : w_hh[(512+col)*HH + k - 256];
    unsigned short h = f2bf(v);
    hi[j] = (short)h;
    lo[j] = (short)f2bf(v - bf2f(h));
  }
  *(short8v*)&wp_hi[(size_t)idx*8] = *(short8v*)hi;
  *(short8v*)&wp_lo[(size_t)idx*8] = *(short8v*)lo;
}

// ---------------- the per-step kernel ----------------
// One dispatch per horizon step; 256 blocks x 1024 threads (16 waves -> 50%
// occupancy); block owns nodes [16b, 16b+16) END-TO-END, no cross-block deps:
//  A: CSR gather + table lerp -> t (LDS)          [reads ring cols s..s+11]
//  B: GRU MFMA 16 rows x 256 cols (1 col-tile/wave), K=512 from LDS t|hc
//  C: pred dot from LDS h' -> out col s, ring col 12+s
__global__ __launch_bounds__(1024) void k_step(
    const int* __restrict__ rowst, const int* __restrict__ csr_src,
    const float* __restrict__ csr_cf, const float* __restrict__ deg,
    float* __restrict__ ring, const float* __restrict__ tab,
    const float* __restrict__ ta_b,
    const float* __restrict__ hc, float* __restrict__ hnb,
    const short* __restrict__ wp_hi, const short* __restrict__ wp_lo,
    const float* __restrict__ b_ih, const float* __restrict__ b_hh,
    const float* __restrict__ out_w, const float* __restrict__ out_b,
    float* __restrict__ out, int s){

  // 260-float row stride: stride%32 = 4 banks -> low-order aliasing only
  __shared__ __align__(16) float t_pad[16][260];
  __shared__ __align__(16) float h_pad[16][260];
  __shared__ int   sidx[16][12];
  __shared__ float sfrac[16][12];

  const int tid = threadIdx.x;
  const int n0 = blockIdx.x*16;
  const int wv = tid >> 6, lane = tid & 63;

  // ---- stage hc -> LDS (one float4 per thread), CSR gather -> sidx/sfrac ----
  {
    int row = tid >> 6;           // 0..15
    int c0 = (tid & 63)*4;        // 0..252
    *(float4*)&h_pad[row][c0] = *(const float4*)(hc + (size_t)(n0+row)*HH + c0);
  }
  if (tid < 192){
    int r = tid/12, w = tid - r*12;
    int node = n0 + r;
    float dv = 1.0f/sqrtf(deg[node] + 1.0f);
    float acc0 = dv*dv*ring[(size_t)node*RS + s + w];
    int e1 = rowst[node+1];
    for (int e = rowst[node]; e < e1; ++e)
      acc0 += csr_cf[e]*ring[(size_t)csr_src[e]*RS + s + w];
    float u = (acc0 + TA) * ((float)TS/(2.0f*TA));
    u = fminf(fmaxf(u, 0.0f), (float)TS - 0.0005f);
    int i = (int)u;
    sidx[r][w] = i;
    sfrac[r][w] = u - (float)i;
  }
  __syncthreads();

  // ---- table lerp -> t (LDS): 1024 threads, 4 rows x 12 lerps each ----
  {
    int col = tid & 255;
    int r0 = (tid >> 8)*4;
    float tb = ta_b[col];
    #pragma unroll
    for (int rr = 0; rr < 4; ++rr){
      int r = r0 + rr;
      float acc0 = tb;
      #pragma unroll
      for (int w = 0; w < 12; ++w){
        const float* pj = tab + ((size_t)w*(TS+1) + sidx[r][w])*HH + col;
        float v0 = pj[0], v1 = pj[HH];
        acc0 += v0 + sfrac[r][w]*(v1 - v0);
      }
      t_pad[r][col] = acc0 > 0.0f ? acc0 : 0.0f;
    }
  }
  __syncthreads();

  // ---- GRU MFMA: wave wv owns col-tile ct=wv (16 cols), 16 rows, K=512 ----
  f32x4 acc[4];
  #pragma unroll
  for (int g = 0; g < 4; ++g) acc[g] = (f32x4){0.f,0.f,0.f,0.f};

  const int a_row = lane & 15, a_oct = lane >> 4;

  #pragma unroll
  for (int ks = 0; ks < 16; ++ks){
    const float* ap = (ks < 8) ? &t_pad[a_row][ks*32 + a_oct*8]
                               : &h_pad[a_row][(ks-8)*32 + a_oct*8];
    float4 x0 = *(const float4*)ap;
    float4 x1 = *(const float4*)(ap+4);
    short8v ah, al;
    cvt8(x0, x1, &ah, &al);
    const int G2 = (ks < 8) ? 2 : 3;
    const size_t fb = (((size_t)ks*4)*16 + (size_t)wv)*64 + lane;
    short8v b0h = *(const short8v*)&wp_hi[(fb + (size_t)0*16*64)*8];
    short8v b0l = *(const short8v*)&wp_lo[(fb + (size_t)0*16*64)*8];
    short8v b1h = *(const short8v*)&wp_hi[(fb + (size_t)1*16*64)*8];
    short8v b1l = *(const short8v*)&wp_lo[(fb + (size_t)1*16*64)*8];
    short8v b2h = *(const short8v*)&wp_hi[(fb + (size_t)G2*16*64)*8];
    short8v b2l = *(const short8v*)&wp_lo[(fb + (size_t)G2*16*64)*8];
    acc[0]  = __builtin_amdgcn_mfma_f32_16x16x32_bf16(ah, b0h, acc[0], 0,0,0);
    acc[0]  = __builtin_amdgcn_mfma_f32_16x16x32_bf16(al, b0h, acc[0], 0,0,0);
    acc[0]  = __builtin_amdgcn_mfma_f32_16x16x32_bf16(ah, b0l, acc[0], 0,0,0);
    acc[1]  = __builtin_amdgcn_mfma_f32_16x16x32_bf16(ah, b1h, acc[1], 0,0,0);
    acc[1]  = __builtin_amdgcn_mfma_f32_16x16x32_bf16(al, b1h, acc[1], 0,0,0);
    acc[1]  = __builtin_amdgcn_mfma_f32_16x16x32_bf16(ah, b1l, acc[1], 0,0,0);
    acc[G2] = __builtin_amdgcn_mfma_f32_16x16x32_bf16(ah, b2h, acc[G2], 0,0,0);
    acc[G2] = __builtin_amdgcn_mfma_f32_16x16x32_bf16(al, b2h, acc[G2], 0,0,0);
    acc[G2] = __builtin_amdgcn_mfma_f32_16x16x32_bf16(ah, b2l, acc[G2], 0,0,0);
  }
  __syncthreads();   // all waves done reading t_pad before epilogue overwrites it

  // ---- epilogue: gates + h' -> global hnb + LDS (t_pad reused as h') ----
  {
    const int ecl  = lane & 15;
    const int erow = (lane >> 4)*4;
    const int col  = wv*16 + ecl;
    float br  = b_ih[col]        + b_hh[col];
    float bz  = b_ih[col + HH]   + b_hh[col + HH];
    float bxn = b_ih[col + 2*HH];
    float bhn = b_hh[col + 2*HH];
    #pragma unroll
    for (int q = 0; q < 4; ++q){
      int row = erow + q;
      float r = fast_sigmoid(acc[0][q] + br);
      float z = fast_sigmoid(acc[1][q] + bz);
      float n = fast_tanh(acc[2][q] + bxn + r*(acc[3][q] + bhn));
      float hv = h_pad[row][col];
      float hp = (1.0f - z)*n + z*hv;
      hnb[(size_t)(n0+row)*HH + col] = hp;
      t_pad[row][col] = hp;
    }
  }
  __syncthreads();

  // ---- pred: wave wv owns row wv; h' . out_w + out_b -> out, ring ----
  {
    int c0 = lane*4;
    float4 hv = *(const float4*)&t_pad[wv][c0];
    float4 w4 = *(const float4*)(out_w + c0);
    float sacc = hv.x*w4.x + hv.y*w4.y + hv.z*w4.z + hv.w*w4.w;
    sacc += __shfl_xor(sacc, 1, 64);
    sacc += __shfl_xor(sacc, 2, 64);
    sacc += __shfl_xor(sacc, 4, 64);
    sacc += __shfl_xor(sacc, 8, 64);
    sacc += __shfl_xor(sacc, 16, 64);
    sacc += __shfl_xor(sacc, 32, 64);
    if (lane == 0){
      float pv = sacc + out_b[0];
      out[(size_t)(n0+wv)*PP + s] = pv;
      ring[(size_t)(n0+wv)*RS + 12 + s] = pv;
    }
  }
}

// ---------------- launcher ----------------

extern "C" void kernel_launch(void* const* d_in, const int* in_sizes, int n_in,
                              void* d_out, int out_size, void* d_ws, size_t ws_size,
                              hipStream_t stream){
  const float* x     = (const float*)d_in[0];
  const int*   ei    = (const int*)  d_in[1];
  const float* ew    = (const float*)d_in[2];
  const float* gcn_w = (const float*)d_in[3];
  const float* ta_w  = (const float*)d_in[4];
  const float* ta_b  = (const float*)d_in[5];
  const float* w_ih  = (const float*)d_in[6];
  const float* w_hh  = (const float*)d_in[7];
  const float* b_ih  = (const float*)d_in[8];
  const float* b_hh  = (const float*)d_in[9];
  const float* out_w = (const float*)d_in[10];
  const float* out_b = (const float*)d_in[11];
  float* out = (float*)d_out;

  char* p = (char*)d_ws;
  float* tab     = (float*)p; p += (size_t)12*(TS+1)*HH*4; // 2.37 MB
  int*   keys    = (int*)p;   p += (size_t)HS*4;
  int*   midx    = (int*)p;   p += (size_t)HS*4;
  int*   wsrc    = (int*)p;   p += (size_t)EE*4;
  int*   wdst    = (int*)p;   p += (size_t)EE*4;
  float* wwt     = (float*)p; p += (size_t)EE*4;
  int*   csr_src = (int*)p;   p += (size_t)EE*4;
  float* csr_cf  = (float*)p; p += (size_t)EE*4;
  float* deg     = (float*)p; p += (size_t)NN*4;
  int*   cnt     = (int*)p;   p += (size_t)NN*4;
  int*   fill    = (int*)p;   p += (size_t)NN*4;
  int*   rowst   = (int*)p;   p += (size_t)(NN+64)*4;
  int*   count   = (int*)p;   p += 256;
  float* ring    = (float*)p; p += (size_t)NN*RS*4;
  float* hA      = (float*)p; p += (size_t)NN*HH*4;
  float* hB      = (float*)p; p += (size_t)NN*HH*4;
  short* wp_hi   = (short*)p; p += (size_t)16*4*16*64*8*2; // 1 MB
  short* wp_lo   = (short*)p; p += (size_t)16*4*16*64*8*2; // 1 MB

  k_init   <<<(NN*HH)/256, 256, 0, stream>>>(x, keys, midx, deg, cnt, ring, hA, count);
  k_insert <<<EE/256, 256, 0, stream>>>(ei, keys, midx);
  k_compact<<<EE/256, 256, 0, stream>>>(ei, ew, keys, midx, wsrc, wdst, wwt, deg, cnt, count);
  k_scan   <<<1, 1024, 0, stream>>>(cnt, rowst, fill);
  k_scatter<<<EE/256, 256, 0, stream>>>(wsrc, wdst, wwt, deg, fill, csr_src, csr_cf, count);
  k_wpack  <<<256, 256, 0, stream>>>(w_ih, w_hh, wp_hi, wp_lo);
  k_tab    <<<dim3(HH/64, (TS+64)/64, WW), 256, 0, stream>>>(gcn_w, ta_w, tab);

  for (int s = 0; s < PP; ++s){
    const float* hc  = (s & 1) ? hB : hA;
    float*       hnb = (s & 1) ? hA : hB;
    k_step<<<NN/16, 1024, 0, stream>>>(rowst, csr_src, csr_cf, deg, ring, tab,
                                       ta_b, hc, hnb, wp_hi, wp_lo,
                                       b_ih, b_hh, out_w, out_b, out, s);
  }
}